// Round 1
// 177.100 us; speedup vs baseline: 1.0056x; 1.0056x over previous
//
#include <hip/hip_runtime.h>
#include <hip/hip_bf16.h>
#include <stdint.h>

// Problem constants
#define TOKS   262144      // B*S = 32*8192
#define NGRP   16384       // B*G = 32*512
#define EMB    1024
#define HD     64

using bf16x8 = __attribute__((ext_vector_type(8))) short;   // 8 bf16 (4 VGPRs) MFMA operand
using f32x4  = __attribute__((ext_vector_type(4))) float;   // MFMA accumulator

__device__ __forceinline__ unsigned pack2(float a, float b) {
    union { __hip_bfloat162 h; unsigned u; } cvt;
    cvt.h = __float22bfloat162_rn(make_float2(a, b));   // RNE pk-convert
    return cvt.u;
}
__device__ __forceinline__ bf16x8 cvt8(float4 v0, float4 v1) {
    uint4 u;
    u.x = pack2(v0.x, v0.y);
    u.y = pack2(v0.z, v0.w);
    u.z = pack2(v1.x, v1.y);
    u.w = pack2(v1.z, v1.w);
    return __builtin_bit_cast(bf16x8, u);
}
__device__ __forceinline__ void gload_lds16(const unsigned short* g, unsigned short* l) {
    __builtin_amdgcn_global_load_lds(
        (const __attribute__((address_space(1))) void*)g,
        (__attribute__((address_space(3))) void*)l,
        16, 0, 0);
}

// ---------------------------------------------------------------------------
// K0: convert Wo (fp32 [1024][1024]) -> bf16  (blocks 0..1023)
//     and Wq|Wk|Wv (fp32 [64][64] each) -> bf16 packed [3][4096] (blocks 1024..1035)
// ---------------------------------------------------------------------------
__global__ __launch_bounds__(256) void k_cvt(const float* __restrict__ wo,
                                             const float* __restrict__ wq,
                                             const float* __restrict__ wk,
                                             const float* __restrict__ wv,
                                             unsigned short* __restrict__ wob,
                                             unsigned short* __restrict__ wqkvb) {
    int bid = blockIdx.x;
    if (bid < 1024) {
        int idx = (bid * 256 + threadIdx.x) * 4;
        float4 v = *(const float4*)(wo + idx);
        uint2 p;
        p.x = pack2(v.x, v.y);
        p.y = pack2(v.z, v.w);
        *(uint2*)(wob + idx) = p;
    } else {
        int b = bid - 1024;                 // 0..11
        int m = b >> 2;
        const float* src = (m == 0) ? wq : ((m == 1) ? wk : wv);
        int idx = ((b & 3) * 256 + threadIdx.x) * 4;
        float4 v = *(const float4*)(src + idx);
        uint2 p;
        p.x = pack2(v.x, v.y);
        p.y = pack2(v.z, v.w);
        *(uint2*)(wqkvb + m * 4096 + idx) = p;
    }
}

// ---------------------------------------------------------------------------
// K1: FUSED QKV projection + 16x16 attention, MFMA throughout. (unchanged)
// ---------------------------------------------------------------------------
#define SCL 0.0450842200278f   /* log2(e)/32 */

__global__ __launch_bounds__(256) void k_fused(const float* __restrict__ x,
                                               const unsigned short* __restrict__ wqkv,
                                               unsigned short* __restrict__ out2) {
    __shared__ __align__(16) unsigned short qkls[4][2][2][16 * 72];
    int t = threadIdx.x;
    int w = t >> 6, l = t & 63;
    int c = l & 15, q = l >> 4;
    int waveTok0 = blockIdx.x * 128 + w * 32;

    bf16x8 xa[2][2];
    #pragma unroll
    for (int g = 0; g < 2; ++g) {
        const float* xp = x + (size_t)(waveTok0 + g * 16 + c) * 64 + q * 8;
        #pragma unroll
        for (int kc = 0; kc < 2; ++kc) {
            float4 v0 = *(const float4*)(xp + kc * 32);
            float4 v1 = *(const float4*)(xp + kc * 32 + 4);
            xa[g][kc] = cvt8(v0, v1);
        }
    }

    uint2 pkV[2][4];
    #pragma unroll
    for (int m = 0; m < 3; ++m) {
        #pragma unroll
        for (int nb = 0; nb < 4; ++nb) {
            const unsigned short* wp = wqkv + m * 4096 + (nb * 16 + c) * 64 + q * 8;
            bf16x8 w0 = *(const bf16x8*)(wp);
            bf16x8 w1 = *(const bf16x8*)(wp + 32);
            #pragma unroll
            for (int g = 0; g < 2; ++g) {
                f32x4 acc = (f32x4){0.f, 0.f, 0.f, 0.f};
                acc = __builtin_amdgcn_mfma_f32_16x16x32_bf16(xa[g][0], w0, acc, 0, 0, 0);
                acc = __builtin_amdgcn_mfma_f32_16x16x32_bf16(xa[g][1], w1, acc, 0, 0, 0);
                unsigned u01 = pack2(acc[0], acc[1]);
                unsigned u23 = pack2(acc[2], acc[3]);
                if (m < 2) {
                    unsigned short* tile = qkls[w][g][m];
                    int base = 4 * q * 72 + nb * 16 + c;
                    tile[base]       = (unsigned short)u01;
                    tile[base + 72]  = (unsigned short)(u01 >> 16);
                    tile[base + 144] = (unsigned short)u23;
                    tile[base + 216] = (unsigned short)(u23 >> 16);
                } else {
                    pkV[g][nb].x = u01;
                    pkV[g][nb].y = u23;
                }
            }
        }
    }

    f32x4 e[2];
    #pragma unroll
    for (int g = 0; g < 2; ++g) {
        const unsigned short* Qt = qkls[w][g][0];
        const unsigned short* Kt = qkls[w][g][1];
        e[g] = (f32x4){0.f, 0.f, 0.f, 0.f};
        #pragma unroll
        for (int kc = 0; kc < 2; ++kc) {
            bf16x8 ka = *(const bf16x8*)(Kt + c * 72 + kc * 32 + q * 8);
            bf16x8 qb = *(const bf16x8*)(Qt + c * 72 + kc * 32 + q * 8);
            e[g] = __builtin_amdgcn_mfma_f32_16x16x32_bf16(ka, qb, e[g], 0, 0, 0);
        }
    }

    unsigned pa0[2], pa1[2];
    #pragma unroll
    for (int g = 0; g < 2; ++g) {
        float mx = fmaxf(fmaxf(e[g][0], e[g][1]), fmaxf(e[g][2], e[g][3]));
        mx = fmaxf(mx, __shfl_xor(mx, 16));
        mx = fmaxf(mx, __shfl_xor(mx, 32));
        float p0 = exp2f((e[g][0] - mx) * SCL);
        float p1 = exp2f((e[g][1] - mx) * SCL);
        float p2 = exp2f((e[g][2] - mx) * SCL);
        float p3 = exp2f((e[g][3] - mx) * SCL);
        float s = p0 + p1 + p2 + p3;
        s += __shfl_xor(s, 16);
        s += __shfl_xor(s, 32);
        float rinv = 1.0f / s;
        pa0[g] = pack2(p0 * rinv, p1 * rinv);
        pa1[g] = pack2(p2 * rinv, p3 * rinv);
    }

    int s0 = (32 * q + c) & 63;
    int s1 = (32 * q + 16 + c) & 63;
    int v0 = 32 * (q & 1) + c;
    int v1 = v0 + 16;
    bool hi = (q >= 2);
    #pragma unroll
    for (int g = 0; g < 2; ++g) {
        int a0 = __shfl((int)pa0[g], s0);
        int a1 = __shfl((int)pa1[g], s0);
        int a2 = __shfl((int)pa0[g], s1);
        int a3 = __shfl((int)pa1[g], s1);
        uint4 A2u;
        A2u.x = hi ? 0u : (unsigned)a0;
        A2u.y = hi ? 0u : (unsigned)a1;
        A2u.z = hi ? 0u : (unsigned)a2;
        A2u.w = hi ? 0u : (unsigned)a3;
        bf16x8 A2 = __builtin_bit_cast(bf16x8, A2u);

        unsigned short* Ot = qkls[w][g][0];
        #pragma unroll
        for (int nb = 0; nb < 4; ++nb) {
            uint4 B2u;
            B2u.x = (unsigned)__shfl((int)pkV[g][nb].x, v0);
            B2u.y = (unsigned)__shfl((int)pkV[g][nb].y, v0);
            B2u.z = (unsigned)__shfl((int)pkV[g][nb].x, v1);
            B2u.w = (unsigned)__shfl((int)pkV[g][nb].y, v1);
            bf16x8 B2 = __builtin_bit_cast(bf16x8, B2u);
            f32x4 o = (f32x4){0.f, 0.f, 0.f, 0.f};
            o = __builtin_amdgcn_mfma_f32_16x16x32_bf16(A2, B2, o, 0, 0, 0);
            unsigned u01 = pack2(o[0], o[1]);
            unsigned u23 = pack2(o[2], o[3]);
            int base = 4 * q * 72 + nb * 16 + c;
            Ot[base]       = (unsigned short)u01;
            Ot[base + 72]  = (unsigned short)(u01 >> 16);
            Ot[base + 144] = (unsigned short)u23;
            Ot[base + 216] = (unsigned short)(u23 >> 16);
        }
    }

    #pragma unroll
    for (int g = 0; g < 2; ++g) {
        int gi = (waveTok0 >> 4) + g;
        int b    = gi >> 9;
        int grem = gi & 511;
        int rowbase = b * 512 + (grem >> 4);
        int colpref = (grem & 15) * 64;
        const unsigned short* osrc = qkls[w][g][0] + (l >> 2) * 72 + (l & 3) * 16;
        uint4 ov0 = *(const uint4*)(osrc);
        uint4 ov1 = *(const uint4*)(osrc + 8);
        unsigned short* dst = out2 + (size_t)(rowbase + (l >> 2) * 32) * 1024
                                   + colpref + (l & 3) * 16;
        *(uint4*)(dst)     = ov0;
        *(uint4*)(dst + 8) = ov1;
    }
}

// ---------------------------------------------------------------------------
// K2: C[16384][1024] = out2 @ Wo^T + bo  (bf16 MFMA, fp32 acc/out)
// 256x256 tile, BK=64, 512 threads (8 waves, 2Mx4N), 8-phase schedule
// (T1+T2+T3+T4+T5 per the CDNA4 guide):
//   - double-buffered 128 KiB LDS (As[2]/Bs[2], each 256x64 bf16)
//   - per phase: {ds_read subtile || stage one half-tile via global_load_lds
//     -> s_barrier -> lgkmcnt(0) -> setprio(1) -> 16 MFMA (one C-quadrant)
//     -> setprio(0) -> s_barrier}
//   - counted s_waitcnt vmcnt(4) ONLY at phases 4 and 8 (never drained to 0
//     in the main loop); last iteration peeled with vmcnt(0) at phase 4.
//   - XOR chunk swizzle (j ^= row&7) on BOTH the pre-swizzled global source
//     and the ds_read address (gload_lds dest stays linear) -> 0 bank conflicts.
//   - quadrant order (0,0)(0,1)(1,1)(1,0): one A reg set + two B reg sets.
//   - bijective XCD swizzle (nwg=256 % 8 == 0), band-major: each XCD owns a
//     contiguous m-band, 4 n-tiles share each 512 KB A panel in its L2.
// ---------------------------------------------------------------------------
#define STG(gb, lb, half, kt) do { \
    gload_lds16((gb) + (size_t)(half) * 131072 + (size_t)(kt) * 64 + ga0, \
                (lb) + (half) * 8192 + lo0); \
    gload_lds16((gb) + (size_t)(half) * 131072 + (size_t)(kt) * 64 + ga1, \
                (lb) + (half) * 8192 + lo1); \
} while (0)

#define LDA4(buf, mh) do { \
    _Pragma("unroll") \
    for (int i2 = 0; i2 < 4; ++i2) { \
        const unsigned short* _p = (buf) + (wrow + ((mh) * 4 + i2) * 16 + lm) * 64; \
        a[i2][0] = *(const bf16x8*)(_p + jo0); \
        a[i2][1] = *(const bf16x8*)(_p + jo1); \
    } \
} while (0)

#define LDB2(dst, buf, nh) do { \
    _Pragma("unroll") \
    for (int j2 = 0; j2 < 2; ++j2) { \
        const unsigned short* _p = (buf) + (wcol + ((nh) * 2 + j2) * 16 + lm) * 64; \
        dst[j2][0] = *(const bf16x8*)(_p + jo0); \
        dst[j2][1] = *(const bf16x8*)(_p + jo1); \
    } \
} while (0)

#define MM8(mh, nh, B) do { \
    _Pragma("unroll") \
    for (int i2 = 0; i2 < 4; ++i2) { \
        _Pragma("unroll") \
        for (int j2 = 0; j2 < 2; ++j2) { \
            acc[(mh)*4+i2][(nh)*2+j2] = __builtin_amdgcn_mfma_f32_16x16x32_bf16( \
                a[i2][0], B[j2][0], acc[(mh)*4+i2][(nh)*2+j2], 0, 0, 0); \
            acc[(mh)*4+i2][(nh)*2+j2] = __builtin_amdgcn_mfma_f32_16x16x32_bf16( \
                a[i2][1], B[j2][1], acc[(mh)*4+i2][(nh)*2+j2], 0, 0, 0); \
        } \
    } \
} while (0)

#define PHASE_MID() do { \
    __builtin_amdgcn_s_barrier(); \
    asm volatile("s_waitcnt lgkmcnt(0)" ::: "memory"); \
    __builtin_amdgcn_sched_barrier(0); \
    __builtin_amdgcn_s_setprio(1); \
} while (0)

#define PHASE_END() do { \
    __builtin_amdgcn_s_setprio(0); \
    __builtin_amdgcn_s_barrier(); \
} while (0)

__global__ __launch_bounds__(512, 2) void k_gemm256(const unsigned short* __restrict__ A,
                                                    const unsigned short* __restrict__ Bm,
                                                    const float* __restrict__ bias,
                                                    float* __restrict__ C) {
    extern __shared__ __align__(16) unsigned short lds[];
    unsigned short* As0 = lds;                 // [256][64] bf16, even K-tile A
    unsigned short* As1 = lds + 16384;         // odd K-tile A
    unsigned short* Bs0 = lds + 32768;         // even K-tile B
    unsigned short* Bs1 = lds + 49152;         // odd K-tile B

    const int t = threadIdx.x;
    const int w = t >> 6, l = t & 63;
    const int lm = l & 15, q4 = l >> 4;
    const int jxor = lm & 7;
    const int jo0 = ((0 + q4) ^ jxor) * 8;     // kc=0 chunk (swizzled)
    const int jo1 = ((4 + q4) ^ jxor) * 8;     // kc=1 chunk (swizzled)

    // bijective XCD swizzle (nwg = 256, divisible by 8)
    const int bid = blockIdx.x;
    const int wg  = (bid & 7) * 32 + (bid >> 3);
    const int m0  = (wg >> 2) * 256;
    const int n0  = (wg & 3) * 256;

    const int wrow = (w >> 2) * 128;           // wave's M offset in tile
    const int wcol = (w & 3) * 64;             // wave's N offset in tile

    // staging slots: s = w*128 + q*64 + l covers 1024 x 16B chunks of a half-tile
    const int s1 = w * 128 + l;
    const int s2 = s1 + 64;
    const int r0 = s1 >> 3, c0 = s1 & 7;
    const int r1 = s2 >> 3, c1 = s2 & 7;
    // global source pre-swizzled (chunk ^ row&7); LDS dest stays linear
    const size_t ga0 = (size_t)r0 * 1024 + (size_t)((c0 ^ (r0 & 7)) * 8);
    const size_t ga1 = (size_t)r1 * 1024 + (size_t)((c1 ^ (r1 & 7)) * 8);
    const int lo0 = s1 * 8;
    const int lo1 = s2 * 8;

    const unsigned short* Ab = A  + (size_t)m0 * 1024;
    const unsigned short* Bb = Bm + (size_t)n0 * 1024;

    f32x4 acc[8][4];
    #pragma unroll
    for (int mi = 0; mi < 8; ++mi)
        #pragma unroll
        for (int ni = 0; ni < 4; ++ni)
            acc[mi][ni] = (f32x4){0.f, 0.f, 0.f, 0.f};

    bf16x8 a[4][2], b0[2][2], b1[2][2];

    // ---- prologue: tile0 A+B, tile1 B; leave tile1 B in flight ----
    STG(Ab, As0, 0, 0); STG(Ab, As0, 1, 0);
    STG(Bb, Bs0, 0, 0); STG(Bb, Bs0, 1, 0);
    STG(Bb, Bs1, 0, 1); STG(Bb, Bs1, 1, 1);
    asm volatile("s_waitcnt vmcnt(4)" ::: "memory");   // tile0 landed
    __builtin_amdgcn_s_barrier();

    #pragma unroll 1
    for (int it = 0; it < 8; ++it) {
        const int kt1 = 2 * it + 1;
        const int kt2 = 2 * it + 2;
        const int kt3 = 2 * it + 3;
        const bool more = (it < 7);

        // ================= even K-tile (buf0) =================
        // p1: Q(0,0)  reads A-mh0 + B-nh0   stages A0(odd)->As1
        LDA4(As0, 0); LDB2(b0, Bs0, 0);
        STG(Ab, As1, 0, kt1);
        PHASE_MID(); MM8(0, 0, b0); PHASE_END();

        // p2: Q(0,1)  reads B-nh1           stages A1(odd)->As1
        LDB2(b1, Bs0, 1);
        STG(Ab, As1, 1, kt1);
        PHASE_MID(); MM8(0, 1, b1); PHASE_END();

        // p3: Q(1,1)  reads A-mh1           stages B0(t+2)->Bs0
        LDA4(As0, 1);
        if (more) STG(Bb, Bs0, 0, kt2);
        PHASE_MID(); MM8(1, 1, b1); PHASE_END();

        // p4: Q(1,0)  (regs held)           stages B1(t+2)->Bs0; counted wait
        if (more) STG(Bb, Bs0, 1, kt2);
        PHASE_MID(); MM8(1, 0, b0);
        __builtin_amdgcn_s_setprio(0);
        if (more) { asm volatile("s_waitcnt vmcnt(4)" ::: "memory"); }
        else      { asm volatile("s_waitcnt vmcnt(0)" ::: "memory"); }
        __builtin_amdgcn_s_barrier();

        // ================= odd K-tile (buf1) =================
        // p5: Q(0,0)                         stages A0(t+2)->As0
        LDA4(As1, 0); LDB2(b0, Bs1, 0);
        if (more) STG(Ab, As0, 0, kt2);
        PHASE_MID(); MM8(0, 0, b0); PHASE_END();

        // p6: Q(0,1)                         stages A1(t+2)->As0
        LDB2(b1, Bs1, 1);
        if (more) STG(Ab, As0, 1, kt2);
        PHASE_MID(); MM8(0, 1, b1); PHASE_END();

        // p7: Q(1,1)                         stages B0(t+3)->Bs1
        LDA4(As1, 1);
        if (more) STG(Bb, Bs1, 0, kt3);
        PHASE_MID(); MM8(1, 1, b1); PHASE_END();

        // p8: Q(1,0)                         stages B1(t+3)->Bs1; counted wait
        if (more) STG(Bb, Bs1, 1, kt3);
        PHASE_MID(); MM8(1, 0, b0);
        __builtin_amdgcn_s_setprio(0);
        if (more) { asm volatile("s_waitcnt vmcnt(4)" ::: "memory"); }
        __builtin_amdgcn_s_barrier();
    }

    // ---- epilogue: bias + fp32 store (16-lane coalesced per col group) ----
    #pragma unroll
    for (int ni = 0; ni < 4; ++ni) {
        const int col = n0 + wcol + ni * 16 + lm;
        const float bcol = bias[col];
        #pragma unroll
        for (int mi = 0; mi < 8; ++mi) {
            #pragma unroll
            for (int r = 0; r < 4; ++r) {
                const int row = m0 + wrow + mi * 16 + q4 * 4 + r;
                C[(size_t)row * 1024 + col] = acc[mi][ni][r] + bcol;
            }
        }
    }
}

// ---------------------------------------------------------------------------
extern "C" void kernel_launch(void* const* d_in, const int* in_sizes, int n_in,
                              void* d_out, int out_size, void* d_ws, size_t ws_size,
                              hipStream_t stream) {
    const float* x  = (const float*)d_in[0];
    const float* wq = (const float*)d_in[1];
    const float* wk = (const float*)d_in[2];
    const float* wv = (const float*)d_in[3];
    const float* wo = (const float*)d_in[4];
    const float* bo = (const float*)d_in[5];
    float* out = (float*)d_out;

    unsigned short* out2  = (unsigned short*)d_ws;           // 16384*1024 bf16 (32 MB)
    unsigned short* wob   = out2 + (size_t)NGRP * 1024;      // 1024*1024 bf16 (2 MB)
    unsigned short* wqkvb = wob + (size_t)EMB * EMB;         // 3*4096 bf16 (24 KB)

    static int s_once = []() {
        hipFuncSetAttribute((const void*)k_gemm256,
                            hipFuncAttributeMaxDynamicSharedMemorySize, 131072);
        return 0;
    }();
    (void)s_once;

    k_cvt    <<<1036, 256, 0, stream>>>(wo, wq, wk, wv, wob, wqkvb);
    k_fused  <<<2048, 256, 0, stream>>>(x, wqkvb, out2);
    k_gemm256<<<256, 512, 131072, stream>>>(out2, wob, bo, out);
}